// Round 1
// baseline (1449.554 us; speedup 1.0000x reference)
//
#include <hip/hip_runtime.h>
#include <hip/hip_bf16.h>

#define DIM 384
#define HEADS 12
#define NTOK 49
#define TOKENS 3137
#define M_ATTN 100352   // 32*64*49 window rows
#define M_FULL 100384   // 32*3137 token rows
#define M_PAD  100480   // 785*128
#define SCALEQ 0.17677669529663687f

typedef __attribute__((ext_vector_type(8))) short s8v;
typedef __attribute__((ext_vector_type(4))) float f4v;
typedef unsigned short u16;

__device__ __forceinline__ float b2f(int s) {
  union { unsigned u; float f; } c; c.u = ((unsigned)(s & 0xffff)) << 16; return c.f;
}
__device__ __forceinline__ u16 f2b(float f) {
  __hip_bfloat16 h = __float2bfloat16(f);
  return *reinterpret_cast<u16*>(&h);
}

// ---------------- weight convert: f32 -> bf16, transposed to [N][K] ----------------
__global__ void k_convert(const float* __restrict__ qkv_w, const float* __restrict__ qkv_b,
                          const float* __restrict__ proj_w, const float* __restrict__ fc1_w,
                          const float* __restrict__ fc2_w,
                          u16* __restrict__ wt_qkv, float* __restrict__ qkvb_s,
                          u16* __restrict__ wt_proj, u16* __restrict__ wt_fc1,
                          u16* __restrict__ wt_fc2) {
  int i = blockIdx.x * 256 + threadIdx.x;
  if (i < 1152 * 384) { int n = i / 384, k = i % 384;
    float v = qkv_w[(size_t)k * 1152 + n]; if (n < 384) v *= SCALEQ; wt_qkv[i] = f2b(v); }
  if (i < 1152) qkvb_s[i] = qkv_b[i] * (i < 384 ? SCALEQ : 1.0f);
  if (i < 384 * 384) { int n = i / 384, k = i % 384; wt_proj[i] = f2b(proj_w[(size_t)k * 384 + n]); }
  if (i < 1536 * 384) { int n = i / 384, k = i % 384; wt_fc1[i] = f2b(fc1_w[(size_t)k * 1536 + n]); }
  if (i < 384 * 1536) { int n = i / 1536, k = i % 1536; wt_fc2[i] = f2b(fc2_w[(size_t)k * 384 + n]); }
}

// ---------------- LN1 + roll(-3,-3) + window partition -> xw bf16 ----------------
__global__ void k_ln1(const float* __restrict__ x, const float* __restrict__ g,
                      const float* __restrict__ b, u16* __restrict__ xw, int t0) {
  int wid = threadIdx.x >> 6, lane = threadIdx.x & 63;
  int t = t0 + blockIdx.x * 4 + wid;          // global window-row index
  int bi = t / 3136, rem = t % 3136;
  int win = rem / NTOK, n = rem % NTOK;
  int wh = win >> 3, ww = win & 7, ii = n / 7, jj = n % 7;
  int h = (wh * 7 + ii + 3) % 56;
  int w = (ww * 7 + jj + 3) % 56;
  const float* src = x + ((size_t)bi * TOKENS + 1 + h * 56 + w) * DIM;
  float v[6];
  #pragma unroll
  for (int e = 0; e < 6; e++) v[e] = src[lane + e * 64];
  float s = v[0] + v[1] + v[2] + v[3] + v[4] + v[5];
  #pragma unroll
  for (int m = 1; m < 64; m <<= 1) s += __shfl_xor(s, m);
  float mu = s * (1.0f / 384.0f);
  float q = 0.f;
  #pragma unroll
  for (int e = 0; e < 6; e++) { float d = v[e] - mu; q += d * d; }
  #pragma unroll
  for (int m = 1; m < 64; m <<= 1) q += __shfl_xor(q, m);
  float rstd = rsqrtf(q * (1.0f / 384.0f) + 1e-5f);
  u16* dst = xw + (size_t)(t - t0) * DIM;
  #pragma unroll
  for (int e = 0; e < 6; e++) {
    int c = lane + e * 64;
    dst[c] = f2b((v[e] - mu) * rstd * g[c] + b[c]);
  }
}

// ---------------- bf16 MFMA GEMM, B^T weights; MODE 0: bias->bf16, 1: bias+gelu->bf16,
// ---------------- 2: bias + resid(x2b) -> f32 d_out with row guard ----------------
template<int MODE>
__global__ __launch_bounds__(256) void k_gemm(
    const u16* __restrict__ A, const u16* __restrict__ Bt,
    const float* __restrict__ bias, u16* __restrict__ Cb,
    float* __restrict__ outp, const u16* __restrict__ resid,
    int N, int K, int row_off) {
  __shared__ __align__(16) u16 As[128][40];
  __shared__ __align__(16) u16 Bs[128][40];
  int t = threadIdx.x;
  int m0 = blockIdx.y * 128, n0 = blockIdx.x * 128;
  int lane = t & 63, wave = t >> 6;
  int lo = lane & 15, hi = lane >> 4;
  int wr = (wave >> 1) * 64, wc = (wave & 1) * 64;
  f4v acc[4][4];
  #pragma unroll
  for (int m = 0; m < 4; m++)
    #pragma unroll
    for (int n = 0; n < 4; n++) acc[m][n] = (f4v)(0.0f);
  const u16* Ab = A + (size_t)m0 * K;
  const u16* Bb = Bt + (size_t)n0 * K;
  int r0 = t >> 2, sg = (t & 3) * 8;
  for (int kt = 0; kt < K; kt += 32) {
    uint4 va0 = *(const uint4*)(Ab + (size_t)r0 * K + kt + sg);
    uint4 va1 = *(const uint4*)(Ab + (size_t)(r0 + 64) * K + kt + sg);
    uint4 vb0 = *(const uint4*)(Bb + (size_t)r0 * K + kt + sg);
    uint4 vb1 = *(const uint4*)(Bb + (size_t)(r0 + 64) * K + kt + sg);
    __syncthreads();
    *(uint4*)(&As[r0][sg]) = va0;
    *(uint4*)(&As[r0 + 64][sg]) = va1;
    *(uint4*)(&Bs[r0][sg]) = vb0;
    *(uint4*)(&Bs[r0 + 64][sg]) = vb1;
    __syncthreads();
    s8v af[4], bfr[4];
    #pragma unroll
    for (int m = 0; m < 4; m++) af[m] = *(const s8v*)(&As[wr + m * 16 + lo][hi * 8]);
    #pragma unroll
    for (int n = 0; n < 4; n++) bfr[n] = *(const s8v*)(&Bs[wc + n * 16 + lo][hi * 8]);
    #pragma unroll
    for (int m = 0; m < 4; m++)
      #pragma unroll
      for (int n = 0; n < 4; n++)
        acc[m][n] = __builtin_amdgcn_mfma_f32_16x16x32_bf16(af[m], bfr[n], acc[m][n], 0, 0, 0);
  }
  #pragma unroll
  for (int m = 0; m < 4; m++) {
    int grow = m0 + wr + m * 16 + hi * 4;
    #pragma unroll
    for (int n = 0; n < 4; n++) {
      int gcol = n0 + wc + n * 16 + lo;
      float bv = bias[gcol];
      #pragma unroll
      for (int r = 0; r < 4; r++) {
        float val = acc[m][n][r] + bv;
        size_t idx = (size_t)(grow + r) * N + gcol;
        if (MODE == 0) {
          Cb[idx] = f2b(val);
        } else if (MODE == 1) {
          float gl = 0.5f * val * (1.0f + erff(val * 0.70710678118654752f));
          Cb[idx] = f2b(gl);
        } else {
          int orow = grow + r + row_off;
          if (orow < M_FULL) {
            size_t oi = (size_t)orow * DIM + gcol;
            outp[oi] = val + b2f(resid[oi]);
          }
        }
      }
    }
  }
}

// ---------------- attention: one wave per (window, head); lane = query row ----------------
__global__ __launch_bounds__(256) void k_attn(const u16* __restrict__ qkv,
                                              const float* __restrict__ rpb,
                                              u16* __restrict__ ao, int win0) {
  int wid = threadIdx.x >> 6, lane = threadIdx.x & 63;
  int gw = blockIdx.x * 4 + wid;
  int win_l = gw / HEADS, h = gw % HEADS;
  int nw = (win0 + win_l) & 63;               // window id within image
  int wh = nw >> 3, ww = nw & 7;
  size_t rowbase = (size_t)win_l * NTOK;
  int i = lane < NTOK ? lane : 0;
  int ii = i / 7, jj = i % 7;
  int hq = wh * 7 + ii, wq = ww * 7 + jj;
  int reg_i = (hq < 49 ? 0 : (hq < 53 ? 1 : 2)) * 3 + (wq < 49 ? 0 : (wq < 53 ? 1 : 2));
  float Q[32];
  {
    const u16* qp = qkv + (rowbase + i) * 1152 + h * 32;
    #pragma unroll
    for (int d0 = 0; d0 < 32; d0 += 8) {
      s8v v = *(const s8v*)(qp + d0);
      #pragma unroll
      for (int e = 0; e < 8; e++) Q[d0 + e] = b2f(v[e]);
    }
  }
  const u16* kb = qkv + rowbase * 1152 + 384 + h * 32;
  const u16* vb = qkv + rowbase * 1152 + 768 + h * 32;
  float mrun = -1e30f, lrun = 0.0f, O[32];
  #pragma unroll
  for (int d = 0; d < 32; d++) O[d] = 0.0f;
  for (int j = 0; j < NTOK; j++) {
    float s = 0.0f;
    const u16* kp = kb + j * 1152;
    #pragma unroll
    for (int d0 = 0; d0 < 32; d0 += 8) {
      s8v kv = *(const s8v*)(kp + d0);
      #pragma unroll
      for (int e = 0; e < 8; e++) s += Q[d0 + e] * b2f(kv[e]);
    }
    int ji = j / 7, j2 = j % 7;
    int hk = wh * 7 + ji, wk = ww * 7 + j2;
    int reg_j = (hk < 49 ? 0 : (hk < 53 ? 1 : 2)) * 3 + (wk < 49 ? 0 : (wk < 53 ? 1 : 2));
    int rpi = (ii - ji + 6) * 13 + (jj - j2 + 6);
    s += rpb[rpi * HEADS + h];
    if (reg_i != reg_j) s -= 100.0f;
    float mn = fmaxf(mrun, s);
    float corr = __expf(mrun - mn);
    float e = __expf(s - mn);
    lrun = lrun * corr + e;
    const u16* vp = vb + j * 1152;
    #pragma unroll
    for (int d0 = 0; d0 < 32; d0 += 8) {
      s8v vv = *(const s8v*)(vp + d0);
      #pragma unroll
      for (int ee = 0; ee < 8; ee++) O[d0 + ee] = O[d0 + ee] * corr + e * b2f(vv[ee]);
    }
    mrun = mn;
  }
  if (lane < NTOK) {
    float inv = 1.0f / lrun;
    u16* op = ao + (rowbase + lane) * DIM + h * 32;
    #pragma unroll
    for (int d = 0; d < 32; d++) op[d] = f2b(O[d] * inv);
  }
}

// ---------------- un-window + roll(+3,+3) + residual + LN2 -> x2 bf16 (padded rows zeroed) ----
__global__ void k_ln2(const float* __restrict__ x, const u16* __restrict__ proj,
                      const float* __restrict__ g, const float* __restrict__ b,
                      u16* __restrict__ x2b) {
  int wid = threadIdx.x >> 6, lane = threadIdx.x & 63;
  int r = blockIdx.x * 4 + wid;
  u16* dst = x2b + (size_t)r * DIM;
  if (r >= M_FULL) {
    u16 z = f2b(0.0f);
    #pragma unroll
    for (int e = 0; e < 6; e++) dst[lane + e * 64] = z;
    return;
  }
  int bi = r / TOKENS, tk = r % TOKENS;
  const float* xs = x + (size_t)r * DIM;
  float v[6];
  if (tk == 0) {
    #pragma unroll
    for (int e = 0; e < 6; e++) v[e] = xs[lane + e * 64];
  } else {
    int p = tk - 1, hh = p / 56, wp = p % 56;
    int a = (hh + 53) % 56, bw = (wp + 53) % 56;   // inverse roll by +3
    int wh = a / 7, ii = a % 7, w2 = bw / 7, jj = bw % 7;
    size_t prow = ((size_t)bi * 64 + wh * 8 + w2) * NTOK + ii * 7 + jj;
    const u16* ps = proj + prow * DIM;
    #pragma unroll
    for (int e = 0; e < 6; e++) v[e] = xs[lane + e * 64] + b2f(ps[lane + e * 64]);
  }
  float s = v[0] + v[1] + v[2] + v[3] + v[4] + v[5];
  #pragma unroll
  for (int m = 1; m < 64; m <<= 1) s += __shfl_xor(s, m);
  float mu = s * (1.0f / 384.0f);
  float q = 0.f;
  #pragma unroll
  for (int e = 0; e < 6; e++) { float d = v[e] - mu; q += d * d; }
  #pragma unroll
  for (int m = 1; m < 64; m <<= 1) q += __shfl_xor(q, m);
  float rstd = rsqrtf(q * (1.0f / 384.0f) + 1e-5f);
  #pragma unroll
  for (int e = 0; e < 6; e++) {
    int c = lane + e * 64;
    dst[c] = f2b((v[e] - mu) * rstd * g[c] + b[c]);
  }
}

extern "C" void kernel_launch(void* const* d_in, const int* in_sizes, int n_in,
                              void* d_out, int out_size, void* d_ws, size_t ws_size,
                              hipStream_t stream) {
  const float* x      = (const float*)d_in[0];
  const float* n1g    = (const float*)d_in[1];
  const float* n1b    = (const float*)d_in[2];
  const float* qkv_w  = (const float*)d_in[3];
  const float* qkv_b  = (const float*)d_in[4];
  const float* rpb    = (const float*)d_in[5];
  const float* proj_w = (const float*)d_in[6];
  const float* proj_b = (const float*)d_in[7];
  const float* n2g    = (const float*)d_in[8];
  const float* n2b    = (const float*)d_in[9];
  const float* fc1_w  = (const float*)d_in[10];
  const float* fc1_b  = (const float*)d_in[11];
  const float* fc2_w  = (const float*)d_in[12];
  const float* fc2_b  = (const float*)d_in[13];
  float* outp = (float*)d_out;

  auto al = [](size_t v) { return (v + 255) & ~(size_t)255; };
  // pick smallest chunking that fits ws_size (NC1: batch-chunks for attn phase,
  // NC2: row-chunks for MLP). Peak need: (1,1)=775MB ... (16,16)=197MB.
  const int cand[8][2] = {{1,1},{1,2},{2,2},{2,4},{4,4},{4,8},{8,8},{16,16}};
  int NC1 = 16, NC2 = 16;
  for (int ci = 0; ci < 8; ci++) {
    int c1 = cand[ci][0], c2 = cand[ci][1];
    int cbb = (785 + c2 - 1) / c2;
    size_t tot = al(884736) + al(294912) + al(1179648) + al(1179648) + al(4608)
               + al((size_t)(M_ATTN / c1) * 768)
               + al((size_t)(M_ATTN / c1) * 2304)
               + al((size_t)M_ATTN * 768)
               + al((size_t)M_PAD * 768)
               + al((size_t)cbb * 128 * 1536 * 2);
    if (tot <= ws_size) { NC1 = c1; NC2 = c2; break; }
  }
  char* p = (char*)d_ws;
  auto take = [&](size_t bytes) { char* r = p; p += al(bytes); return r; };
  u16* wt_qkv  = (u16*)take(884736);
  u16* wt_proj = (u16*)take(294912);
  u16* wt_fc1  = (u16*)take(1179648);
  u16* wt_fc2  = (u16*)take(1179648);
  float* qkvb_s = (float*)take(4608);
  int chunkM = M_ATTN / NC1;
  u16* XW   = (u16*)take((size_t)chunkM * 768);
  u16* QKV  = (u16*)take((size_t)chunkM * 2304);
  u16* PROJ = (u16*)take((size_t)M_ATTN * 768);
  u16* X2B  = (u16*)take((size_t)M_PAD * 768);
  int cb = (785 + NC2 - 1) / NC2;
  u16* FC1  = (u16*)take((size_t)cb * 128 * 1536 * 2);
  u16* AO = XW;   // alias: XW dead after QKV GEMM, AO written after

  k_convert<<<2304, 256, 0, stream>>>(qkv_w, qkv_b, proj_w, fc1_w, fc2_w,
                                      wt_qkv, qkvb_s, wt_proj, wt_fc1, wt_fc2);
  int chunkWin = chunkM / NTOK;
  for (int c = 0; c < NC1; c++) {
    int t0 = c * chunkM;
    k_ln1<<<chunkM / 4, 256, 0, stream>>>(x, n1g, n1b, XW, t0);
    k_gemm<0><<<dim3(9, chunkM / 128), 256, 0, stream>>>(XW, wt_qkv, qkvb_s, QKV,
                                                         nullptr, nullptr, 1152, 384, 0);
    k_attn<<<chunkWin * HEADS / 4, 256, 0, stream>>>(QKV, rpb, AO, c * chunkWin);
    k_gemm<0><<<dim3(3, chunkM / 128), 256, 0, stream>>>(AO, wt_proj, proj_b,
                                                         PROJ + (size_t)t0 * DIM,
                                                         nullptr, nullptr, 384, 384, 0);
  }
  k_ln2<<<M_PAD / 4, 256, 0, stream>>>(x, PROJ, n2g, n2b, X2B);
  for (int c = 0; c < NC2; c++) {
    int rb0 = c * cb;
    int nb = 785 - rb0; if (nb > cb) nb = cb; if (nb <= 0) break;
    k_gemm<1><<<dim3(12, nb), 256, 0, stream>>>(X2B + (size_t)rb0 * 128 * DIM, wt_fc1,
                                                fc1_b, FC1, nullptr, nullptr, 1536, 384, 0);
    k_gemm<2><<<dim3(3, nb), 256, 0, stream>>>(FC1, wt_fc2, fc2_b, nullptr, outp, X2B,
                                               384, 1536, rb0 * 128);
  }
}

// Round 2
// 1057.461 us; speedup vs baseline: 1.3708x; 1.3708x over previous
//
#include <hip/hip_runtime.h>
#include <hip/hip_bf16.h>

#define DIM 384
#define HEADS 12
#define NTOK 49
#define TOKENS 3137
#define M_ATTN 100352   // 32*64*49 window rows
#define M_FULL 100384   // 32*3137 token rows
#define M_PAD  100480   // 785*128
#define SCALEQ 0.17677669529663687f

typedef __attribute__((ext_vector_type(8))) short s8v;
typedef __attribute__((ext_vector_type(4))) float f4v;
typedef unsigned short u16;

__device__ __forceinline__ float b2f(int s) {
  union { unsigned u; float f; } c; c.u = ((unsigned)(s & 0xffff)) << 16; return c.f;
}
__device__ __forceinline__ u16 f2b(float f) {
  __hip_bfloat16 h = __float2bfloat16(f);
  return *reinterpret_cast<u16*>(&h);
}
__device__ __forceinline__ void gload16(const void* g, void* l) {
  __builtin_amdgcn_global_load_lds((const __attribute__((address_space(1))) void*)g,
                                   (__attribute__((address_space(3))) void*)l, 16, 0, 0);
}

// ---------------- weight convert: f32 -> bf16, transposed to [N][K] ----------------
__global__ void k_convert(const float* __restrict__ qkv_w, const float* __restrict__ qkv_b,
                          const float* __restrict__ proj_w, const float* __restrict__ fc1_w,
                          const float* __restrict__ fc2_w,
                          u16* __restrict__ wt_qkv, float* __restrict__ qkvb_s,
                          u16* __restrict__ wt_proj, u16* __restrict__ wt_fc1,
                          u16* __restrict__ wt_fc2) {
  int i = blockIdx.x * 256 + threadIdx.x;
  if (i < 1152 * 384) { int n = i / 384, k = i % 384;
    float v = qkv_w[(size_t)k * 1152 + n]; if (n < 384) v *= SCALEQ; wt_qkv[i] = f2b(v); }
  if (i < 1152) qkvb_s[i] = qkv_b[i] * (i < 384 ? SCALEQ : 1.0f);
  if (i < 384 * 384) { int n = i / 384, k = i % 384; wt_proj[i] = f2b(proj_w[(size_t)k * 384 + n]); }
  if (i < 1536 * 384) { int n = i / 384, k = i % 384; wt_fc1[i] = f2b(fc1_w[(size_t)k * 1536 + n]); }
  if (i < 384 * 1536) { int n = i / 1536, k = i % 1536; wt_fc2[i] = f2b(fc2_w[(size_t)k * 384 + n]); }
}

// ---------------- ADD table: bias + shift mask per window class ----------------
__global__ void k_addtab(const float* __restrict__ rpb, float* __restrict__ ADD) {
  int idx = blockIdx.x * 256 + threadIdx.x;
  if (idx >= 4 * HEADS * NTOK * NTOK) return;
  int j = idx % NTOK, t = idx / NTOK;
  int i = t % NTOK; t /= NTOK;
  int h = t % HEADS; int cls = t / HEADS;
  int ii = i / 7, jj = i % 7, ji = j / 7, j2 = j % 7;
  int rpi = (ii - ji + 6) * 13 + (jj - j2 + 6);
  float v = rpb[rpi * HEADS + h];
  int rh = (cls & 2) ? (ii < 4 ? 1 : 2) : 0;
  int rw = (cls & 1) ? (jj < 4 ? 1 : 2) : 0;
  int sh = (cls & 2) ? (ji < 4 ? 1 : 2) : 0;
  int sw = (cls & 1) ? (j2 < 4 ? 1 : 2) : 0;
  if (rh != sh || rw != sw) v -= 100.0f;
  ADD[idx] = v;
}

// ---------------- LN1 + roll(-3,-3) + window partition -> xw bf16 ----------------
__global__ void k_ln1(const float* __restrict__ x, const float* __restrict__ g,
                      const float* __restrict__ b, u16* __restrict__ xw, int t0) {
  int wid = threadIdx.x >> 6, lane = threadIdx.x & 63;
  int t = t0 + blockIdx.x * 4 + wid;          // global window-row index
  int bi = t / 3136, rem = t % 3136;
  int win = rem / NTOK, n = rem % NTOK;
  int wh = win >> 3, ww = win & 7, ii = n / 7, jj = n % 7;
  int h = (wh * 7 + ii + 3) % 56;
  int w = (ww * 7 + jj + 3) % 56;
  const float* src = x + ((size_t)bi * TOKENS + 1 + h * 56 + w) * DIM;
  float v[6];
  #pragma unroll
  for (int e = 0; e < 6; e++) v[e] = src[lane + e * 64];
  float s = v[0] + v[1] + v[2] + v[3] + v[4] + v[5];
  #pragma unroll
  for (int m = 1; m < 64; m <<= 1) s += __shfl_xor(s, m);
  float mu = s * (1.0f / 384.0f);
  float q = 0.f;
  #pragma unroll
  for (int e = 0; e < 6; e++) { float d = v[e] - mu; q += d * d; }
  #pragma unroll
  for (int m = 1; m < 64; m <<= 1) q += __shfl_xor(q, m);
  float rstd = rsqrtf(q * (1.0f / 384.0f) + 1e-5f);
  u16* dst = xw + (size_t)(t - t0) * DIM;
  #pragma unroll
  for (int e = 0; e < 6; e++) {
    int c = lane + e * 64;
    dst[c] = f2b((v[e] - mu) * rstd * g[c] + b[c]);
  }
}

// ---------------- bf16 MFMA GEMM (m97-style global_load_lds staging, 16B-slot swizzle)
// MODE 0: bias->bf16, 1: bias+gelu->bf16, 2: bias + resid -> f32 d_out w/ row guard
template<int MODE>
__global__ __launch_bounds__(256) void k_gemm(
    const u16* __restrict__ A, const u16* __restrict__ Bt,
    const float* __restrict__ bias, u16* __restrict__ Cb,
    float* __restrict__ outp, const u16* __restrict__ resid,
    int N, int K, int row_off) {
  __shared__ __align__(16) u16 As[128 * 32];
  __shared__ __align__(16) u16 Bs[128 * 32];
  int t = threadIdx.x;
  int m0 = blockIdx.y * 128, n0 = blockIdx.x * 128;
  int lane = t & 63, wave = t >> 6;
  int lo = lane & 15, hi = lane >> 4;
  int wr = (wave >> 1) * 64, wc = (wave & 1) * 64;
  // staging: wave stages 32 A rows + 32 B rows per K-step via 4 width-16 calls.
  // physical LDS slot s at row r holds logical 16B-col (s ^ (r&3)) -> pre-swizzled source.
  int rl = lane >> 2;                 // row within 16-row chunk
  int sslot = (lane & 3) ^ (rl & 3);  // swizzled global 16B slot
  const u16* Ag0 = A + (size_t)(m0 + wave * 32 + rl) * K + sslot * 8;
  const u16* Ag1 = A + (size_t)(m0 + wave * 32 + 16 + rl) * K + sslot * 8;
  const u16* Bg0 = Bt + (size_t)(n0 + wave * 32 + rl) * K + sslot * 8;
  const u16* Bg1 = Bt + (size_t)(n0 + wave * 32 + 16 + rl) * K + sslot * 8;
  u16* Al0 = As + (wave * 32) * 32;   // wave-uniform LDS bases (linear dest)
  u16* Al1 = As + (wave * 32 + 16) * 32;
  u16* Bl0 = Bs + (wave * 32) * 32;
  u16* Bl1 = Bs + (wave * 32 + 16) * 32;
  f4v acc[4][4];
  #pragma unroll
  for (int m = 0; m < 4; m++)
    #pragma unroll
    for (int n = 0; n < 4; n++) acc[m][n] = (f4v)(0.0f);
  int fsw = (hi ^ (lo & 3)) * 8;      // swizzled fragment 16B slot (u16 units)
  for (int kt = 0; kt < K; kt += 32) {
    __syncthreads();
    gload16(Ag0 + kt, Al0);
    gload16(Ag1 + kt, Al1);
    gload16(Bg0 + kt, Bl0);
    gload16(Bg1 + kt, Bl1);
    __syncthreads();
    s8v af[4], bfr[4];
    #pragma unroll
    for (int m = 0; m < 4; m++) af[m] = *(const s8v*)(As + (wr + m * 16 + lo) * 32 + fsw);
    #pragma unroll
    for (int n = 0; n < 4; n++) bfr[n] = *(const s8v*)(Bs + (wc + n * 16 + lo) * 32 + fsw);
    #pragma unroll
    for (int m = 0; m < 4; m++)
      #pragma unroll
      for (int n = 0; n < 4; n++)
        acc[m][n] = __builtin_amdgcn_mfma_f32_16x16x32_bf16(af[m], bfr[n], acc[m][n], 0, 0, 0);
  }
  #pragma unroll
  for (int m = 0; m < 4; m++) {
    int grow = m0 + wr + m * 16 + hi * 4;
    #pragma unroll
    for (int n = 0; n < 4; n++) {
      int gcol = n0 + wc + n * 16 + lo;
      float bv = bias[gcol];
      #pragma unroll
      for (int r = 0; r < 4; r++) {
        float val = acc[m][n][r] + bv;
        size_t idx = (size_t)(grow + r) * N + gcol;
        if (MODE == 0) {
          Cb[idx] = f2b(val);
        } else if (MODE == 1) {
          float gl = 0.5f * val * (1.0f + erff(val * 0.70710678118654752f));
          Cb[idx] = f2b(gl);
        } else {
          int orow = grow + r + row_off;
          if (orow < M_FULL) {
            size_t oi = (size_t)orow * DIM + gcol;
            outp[oi] = val + b2f(resid[oi]);
          }
        }
      }
    }
  }
}

// ---------------- MFMA attention: one wave per window, 12 heads serial ----------------
__global__ __launch_bounds__(256) void k_attn2(const u16* __restrict__ qkv,
                                               const float* __restrict__ ADD,
                                               u16* __restrict__ ao, int win0) {
  __shared__ u16 PT[4][64][76];   // P transposed: PT[j][i] (+12 pad: 2-way-free banks)
  __shared__ u16 VT[4][32][76];   // V transposed: VT[d][j]
  int wid = threadIdx.x >> 6, lane = threadIdx.x & 63;
  int lo = lane & 15, hi = lane >> 4;
  int win_l = blockIdx.x * 4 + wid;
  int nw = (win0 + win_l) & 63;
  int wh = nw >> 3, ww = nw & 7;
  int cls = ((wh == 7) ? 2 : 0) + ((ww == 7) ? 1 : 0);
  size_t rowbase = (size_t)win_l * NTOK;
  u16 (*pt)[76] = PT[wid];
  u16 (*vt)[76] = VT[wid];

  int rcl[4];
  #pragma unroll
  for (int ti = 0; ti < 4; ti++) {
    int r = ti * 16 + lo;
    rcl[ti] = r < NTOK ? r : NTOK - 1;      // clamped fragment row
  }
  int jrow = lane < NTOK ? lane : NTOK - 1; // clamped V row for staging

  for (int h = 0; h < HEADS; h++) {
    // ---- fragments of Q,K straight from global; S = Q.K^T ----
    s8v af[4], bf[4];
    #pragma unroll
    for (int ti = 0; ti < 4; ti++) {
      af[ti] = *(const s8v*)(qkv + (rowbase + rcl[ti]) * 1152 + h * 32 + hi * 8);
      bf[ti] = *(const s8v*)(qkv + (rowbase + rcl[ti]) * 1152 + 384 + h * 32 + hi * 8);
    }
    f4v st[4][4];
    #pragma unroll
    for (int mi = 0; mi < 4; mi++)
      #pragma unroll
      for (int ni = 0; ni < 4; ni++)
        st[mi][ni] = __builtin_amdgcn_mfma_f32_16x16x32_bf16(af[mi], bf[ni], (f4v)(0.0f), 0, 0, 0);

    // ---- stage V^T into LDS (overlaps with MFMA latency) ----
    {
      const u16* vsrc = qkv + (rowbase + jrow) * 1152 + 768 + h * 32;
      #pragma unroll
      for (int d0 = 0; d0 < 32; d0 += 8) {
        s8v v = *(const s8v*)(vsrc + d0);
        #pragma unroll
        for (int e = 0; e < 8; e++) vt[d0 + e][lane] = (u16)v[e];
      }
    }

    // ---- bias + mask (precomputed), pad cols -> -inf ----
    const float* addb = ADD + ((size_t)cls * HEADS + h) * (NTOK * NTOK);
    #pragma unroll
    for (int mi = 0; mi < 4; mi++)
      #pragma unroll
      for (int ni = 0; ni < 4; ni++) {
        int jj = ni * 16 + lo;
        #pragma unroll
        for (int r = 0; r < 4; r++) {
          int i = mi * 16 + hi * 4 + r;
          if (jj < NTOK) {
            int ic = i < NTOK ? i : NTOK - 1;
            st[mi][ni][r] += addb[ic * NTOK + jj];
          } else st[mi][ni][r] = -1e30f;
        }
      }

    // ---- in-register row softmax (reduce over lo-16 group) ----
    float invl[4][4];
    #pragma unroll
    for (int mi = 0; mi < 4; mi++)
      #pragma unroll
      for (int r = 0; r < 4; r++) {
        float m = fmaxf(fmaxf(st[mi][0][r], st[mi][1][r]), fmaxf(st[mi][2][r], st[mi][3][r]));
        #pragma unroll
        for (int msk = 1; msk < 16; msk <<= 1) m = fmaxf(m, __shfl_xor(m, msk));
        float s = 0.f;
        #pragma unroll
        for (int ni = 0; ni < 4; ni++) {
          float p = __expf(st[mi][ni][r] - m);
          st[mi][ni][r] = p;
          s += p;
        }
        #pragma unroll
        for (int msk = 1; msk < 16; msk <<= 1) s += __shfl_xor(s, msk);
        invl[mi][r] = 1.0f / s;
      }

    // ---- P -> PT bf16 (b64 writes, 4 rows i per write) ----
    #pragma unroll
    for (int ni = 0; ni < 4; ni++)
      #pragma unroll
      for (int mi = 0; mi < 4; mi++) {
        ushort4 pk;
        pk.x = f2b(st[mi][ni][0]); pk.y = f2b(st[mi][ni][1]);
        pk.z = f2b(st[mi][ni][2]); pk.w = f2b(st[mi][ni][3]);
        *(ushort4*)(&pt[ni * 16 + lo][mi * 16 + hi * 4]) = pk;
      }

    // ---- O = P.V ----
    f4v ot[4][2];
    #pragma unroll
    for (int mi = 0; mi < 4; mi++)
      #pragma unroll
      for (int dt = 0; dt < 2; dt++) ot[mi][dt] = (f4v)(0.0f);
    #pragma unroll
    for (int kt = 0; kt < 2; kt++) {
      s8v pa[4], vb[2];
      #pragma unroll
      for (int mi = 0; mi < 4; mi++) {
        s8v p;
        #pragma unroll
        for (int e = 0; e < 8; e++) p[e] = (short)pt[kt * 32 + hi * 8 + e][mi * 16 + lo];
        pa[mi] = p;
      }
      #pragma unroll
      for (int dt = 0; dt < 2; dt++) {
        short4 a = *(const short4*)(&vt[dt * 16 + lo][kt * 32 + hi * 8]);
        short4 b = *(const short4*)(&vt[dt * 16 + lo][kt * 32 + hi * 8 + 4]);
        s8v v; v[0] = a.x; v[1] = a.y; v[2] = a.z; v[3] = a.w;
               v[4] = b.x; v[5] = b.y; v[6] = b.z; v[7] = b.w;
        vb[dt] = v;
      }
      #pragma unroll
      for (int mi = 0; mi < 4; mi++)
        #pragma unroll
        for (int dt = 0; dt < 2; dt++)
          ot[mi][dt] = __builtin_amdgcn_mfma_f32_16x16x32_bf16(pa[mi], vb[dt], ot[mi][dt], 0, 0, 0);
    }

    // ---- scale + store ----
    #pragma unroll
    for (int mi = 0; mi < 4; mi++)
      #pragma unroll
      for (int r = 0; r < 4; r++) {
        int i = mi * 16 + hi * 4 + r;
        if (i < NTOK) {
          u16* op = ao + (rowbase + i) * DIM + h * 32 + lo;
          op[0]  = f2b(ot[mi][0][r] * invl[mi][r]);
          op[16] = f2b(ot[mi][1][r] * invl[mi][r]);
        }
      }
  }
}

// ---------------- un-window + roll(+3,+3) + residual + LN2 -> x2 bf16 ----------------
__global__ void k_ln2(const float* __restrict__ x, const u16* __restrict__ proj,
                      const float* __restrict__ g, const float* __restrict__ b,
                      u16* __restrict__ x2b) {
  int wid = threadIdx.x >> 6, lane = threadIdx.x & 63;
  int r = blockIdx.x * 4 + wid;
  u16* dst = x2b + (size_t)r * DIM;
  if (r >= M_FULL) {
    u16 z = f2b(0.0f);
    #pragma unroll
    for (int e = 0; e < 6; e++) dst[lane + e * 64] = z;
    return;
  }
  int bi = r / TOKENS, tk = r % TOKENS;
  const float* xs = x + (size_t)r * DIM;
  float v[6];
  if (tk == 0) {
    #pragma unroll
    for (int e = 0; e < 6; e++) v[e] = xs[lane + e * 64];
  } else {
    int p = tk - 1, hh = p / 56, wp = p % 56;
    int a = (hh + 53) % 56, bw = (wp + 53) % 56;   // inverse roll by +3
    int wh = a / 7, ii = a % 7, w2 = bw / 7, jj = bw % 7;
    size_t prow = ((size_t)bi * 64 + wh * 8 + w2) * NTOK + ii * 7 + jj;
    const u16* ps = proj + prow * DIM;
    #pragma unroll
    for (int e = 0; e < 6; e++) v[e] = xs[lane + e * 64] + b2f(ps[lane + e * 64]);
  }
  float s = v[0] + v[1] + v[2] + v[3] + v[4] + v[5];
  #pragma unroll
  for (int m = 1; m < 64; m <<= 1) s += __shfl_xor(s, m);
  float mu = s * (1.0f / 384.0f);
  float q = 0.f;
  #pragma unroll
  for (int e = 0; e < 6; e++) { float d = v[e] - mu; q += d * d; }
  #pragma unroll
  for (int m = 1; m < 64; m <<= 1) q += __shfl_xor(q, m);
  float rstd = rsqrtf(q * (1.0f / 384.0f) + 1e-5f);
  #pragma unroll
  for (int e = 0; e < 6; e++) {
    int c = lane + e * 64;
    dst[c] = f2b((v[e] - mu) * rstd * g[c] + b[c]);
  }
}

extern "C" void kernel_launch(void* const* d_in, const int* in_sizes, int n_in,
                              void* d_out, int out_size, void* d_ws, size_t ws_size,
                              hipStream_t stream) {
  const float* x      = (const float*)d_in[0];
  const float* n1g    = (const float*)d_in[1];
  const float* n1b    = (const float*)d_in[2];
  const float* qkv_w  = (const float*)d_in[3];
  const float* qkv_b  = (const float*)d_in[4];
  const float* rpb    = (const float*)d_in[5];
  const float* proj_w = (const float*)d_in[6];
  const float* proj_b = (const float*)d_in[7];
  const float* n2g    = (const float*)d_in[8];
  const float* n2b    = (const float*)d_in[9];
  const float* fc1_w  = (const float*)d_in[10];
  const float* fc1_b  = (const float*)d_in[11];
  const float* fc2_w  = (const float*)d_in[12];
  const float* fc2_b  = (const float*)d_in[13];
  float* outp = (float*)d_out;

  auto al = [](size_t v) { return (v + 255) & ~(size_t)255; };
  const int cand[8][2] = {{1,1},{1,2},{2,2},{2,4},{4,4},{4,8},{8,8},{16,16}};
  int NC1 = 16, NC2 = 16;
  for (int ci = 0; ci < 8; ci++) {
    int c1 = cand[ci][0], c2 = cand[ci][1];
    int cbb = (785 + c2 - 1) / c2;
    size_t tot = al(884736) + al(294912) + al(1179648) + al(1179648) + al(4608)
               + al(460992)
               + al((size_t)(M_ATTN / c1) * 768)
               + al((size_t)(M_ATTN / c1) * 2304)
               + al((size_t)M_ATTN * 768)
               + al((size_t)M_PAD * 768)
               + al((size_t)cbb * 128 * 1536 * 2);
    if (tot <= ws_size) { NC1 = c1; NC2 = c2; break; }
  }
  char* p = (char*)d_ws;
  auto take = [&](size_t bytes) { char* r = p; p += al(bytes); return r; };
  u16* wt_qkv  = (u16*)take(884736);
  u16* wt_proj = (u16*)take(294912);
  u16* wt_fc1  = (u16*)take(1179648);
  u16* wt_fc2  = (u16*)take(1179648);
  float* qkvb_s = (float*)take(4608);
  float* ADDt   = (float*)take(460992);
  int chunkM = M_ATTN / NC1;
  u16* XW   = (u16*)take((size_t)chunkM * 768);
  u16* QKV  = (u16*)take((size_t)chunkM * 2304);
  u16* PROJ = (u16*)take((size_t)M_ATTN * 768);
  u16* X2B  = (u16*)take((size_t)M_PAD * 768);
  int cb = (785 + NC2 - 1) / NC2;
  u16* FC1  = (u16*)take((size_t)cb * 128 * 1536 * 2);
  u16* AO = XW;   // alias: XW dead after QKV GEMM

  k_convert<<<2304, 256, 0, stream>>>(qkv_w, qkv_b, proj_w, fc1_w, fc2_w,
                                      wt_qkv, qkvb_s, wt_proj, wt_fc1, wt_fc2);
  k_addtab<<<451, 256, 0, stream>>>(rpb, ADDt);
  int chunkWin = chunkM / NTOK;
  for (int c = 0; c < NC1; c++) {
    int t0 = c * chunkM;
    k_ln1<<<chunkM / 4, 256, 0, stream>>>(x, n1g, n1b, XW, t0);
    k_gemm<0><<<dim3(9, chunkM / 128), 256, 0, stream>>>(XW, wt_qkv, qkvb_s, QKV,
                                                         nullptr, nullptr, 1152, 384, 0);
    k_attn2<<<chunkWin / 4, 256, 0, stream>>>(QKV, ADDt, AO, c * chunkWin);
    k_gemm<0><<<dim3(3, chunkM / 128), 256, 0, stream>>>(AO, wt_proj, proj_b,
                                                         PROJ + (size_t)t0 * DIM,
                                                         nullptr, nullptr, 384, 384, 0);
  }
  k_ln2<<<M_PAD / 4, 256, 0, stream>>>(x, PROJ, n2g, n2b, X2B);
  for (int c = 0; c < NC2; c++) {
    int rb0 = c * cb;
    int nb = 785 - rb0; if (nb > cb) nb = cb; if (nb <= 0) break;
    k_gemm<1><<<dim3(12, nb), 256, 0, stream>>>(X2B + (size_t)rb0 * 128 * DIM, wt_fc1,
                                                fc1_b, FC1, nullptr, nullptr, 1536, 384, 0);
    k_gemm<2><<<dim3(3, nb), 256, 0, stream>>>(FC1, wt_fc2, fc2_b, nullptr, outp, X2B,
                                               384, 1536, rb0 * 128);
  }
}

// Round 3
// 1012.934 us; speedup vs baseline: 1.4310x; 1.0440x over previous
//
#include <hip/hip_runtime.h>
#include <hip/hip_bf16.h>

#define DIM 384
#define HEADS 12
#define NTOK 49
#define TOKENS 3137
#define M_ATTN 100352   // 32*64*49 window rows
#define M_FULL 100384   // 32*3137 token rows
#define M_PAD  100480   // 785*128
#define SCALEQ 0.17677669529663687f

typedef __attribute__((ext_vector_type(8))) short s8v;
typedef __attribute__((ext_vector_type(4))) float f4v;
typedef unsigned short u16;

__device__ __forceinline__ float b2f(int s) {
  union { unsigned u; float f; } c; c.u = ((unsigned)(s & 0xffff)) << 16; return c.f;
}
__device__ __forceinline__ u16 f2b(float f) {
  __hip_bfloat16 h = __float2bfloat16(f);
  return *reinterpret_cast<u16*>(&h);
}
__device__ __forceinline__ void gload16(const void* g, void* l) {
  __builtin_amdgcn_global_load_lds((const __attribute__((address_space(1))) void*)g,
                                   (__attribute__((address_space(3))) void*)l, 16, 0, 0);
}

// ---------------- weight convert: f32 -> bf16, transposed to [N][K] ----------------
__global__ void k_convert(const float* __restrict__ qkv_w, const float* __restrict__ qkv_b,
                          const float* __restrict__ proj_w, const float* __restrict__ fc1_w,
                          const float* __restrict__ fc2_w,
                          u16* __restrict__ wt_qkv, float* __restrict__ qkvb_s,
                          u16* __restrict__ wt_proj, u16* __restrict__ wt_fc1,
                          u16* __restrict__ wt_fc2) {
  int i = blockIdx.x * 256 + threadIdx.x;
  if (i < 1152 * 384) { int n = i / 384, k = i % 384;
    float v = qkv_w[(size_t)k * 1152 + n]; if (n < 384) v *= SCALEQ; wt_qkv[i] = f2b(v); }
  if (i < 1152) qkvb_s[i] = qkv_b[i] * (i < 384 ? SCALEQ : 1.0f);
  if (i < 384 * 384) { int n = i / 384, k = i % 384; wt_proj[i] = f2b(proj_w[(size_t)k * 384 + n]); }
  if (i < 1536 * 384) { int n = i / 384, k = i % 384; wt_fc1[i] = f2b(fc1_w[(size_t)k * 1536 + n]); }
  if (i < 384 * 1536) { int n = i / 1536, k = i % 1536; wt_fc2[i] = f2b(fc2_w[(size_t)k * 384 + n]); }
}

// ---------------- ADD table: bias + shift mask per window class ----------------
__global__ void k_addtab(const float* __restrict__ rpb, float* __restrict__ ADD) {
  int idx = blockIdx.x * 256 + threadIdx.x;
  if (idx >= 4 * HEADS * NTOK * NTOK) return;
  int j = idx % NTOK, t = idx / NTOK;
  int i = t % NTOK; t /= NTOK;
  int h = t % HEADS; int cls = t / HEADS;
  int ii = i / 7, jj = i % 7, ji = j / 7, j2 = j % 7;
  int rpi = (ii - ji + 6) * 13 + (jj - j2 + 6);
  float v = rpb[rpi * HEADS + h];
  int rh = (cls & 2) ? (ii < 4 ? 1 : 2) : 0;
  int rw = (cls & 1) ? (jj < 4 ? 1 : 2) : 0;
  int sh = (cls & 2) ? (ji < 4 ? 1 : 2) : 0;
  int sw = (cls & 1) ? (j2 < 4 ? 1 : 2) : 0;
  if (rh != sh || rw != sw) v -= 100.0f;
  ADD[idx] = v;
}

// ---------------- LN1 + roll(-3,-3) + window partition -> xw bf16 ----------------
__global__ void k_ln1(const float* __restrict__ x, const float* __restrict__ g,
                      const float* __restrict__ b, u16* __restrict__ xw, int t0) {
  int wid = threadIdx.x >> 6, lane = threadIdx.x & 63;
  int t = t0 + blockIdx.x * 4 + wid;          // global window-row index
  int bi = t / 3136, rem = t % 3136;
  int win = rem / NTOK, n = rem % NTOK;
  int wh = win >> 3, ww = win & 7, ii = n / 7, jj = n % 7;
  int h = (wh * 7 + ii + 3) % 56;
  int w = (ww * 7 + jj + 3) % 56;
  const float* src = x + ((size_t)bi * TOKENS + 1 + h * 56 + w) * DIM;
  float v[6];
  #pragma unroll
  for (int e = 0; e < 6; e++) v[e] = src[lane + e * 64];
  float s = v[0] + v[1] + v[2] + v[3] + v[4] + v[5];
  #pragma unroll
  for (int m = 1; m < 64; m <<= 1) s += __shfl_xor(s, m);
  float mu = s * (1.0f / 384.0f);
  float q = 0.f;
  #pragma unroll
  for (int e = 0; e < 6; e++) { float d = v[e] - mu; q += d * d; }
  #pragma unroll
  for (int m = 1; m < 64; m <<= 1) q += __shfl_xor(q, m);
  float rstd = rsqrtf(q * (1.0f / 384.0f) + 1e-5f);
  u16* dst = xw + (size_t)(t - t0) * DIM;
  #pragma unroll
  for (int e = 0; e < 6; e++) {
    int c = lane + e * 64;
    dst[c] = f2b((v[e] - mu) * rstd * g[c] + b[c]);
  }
}

// ---------------- bf16 MFMA GEMM, BK=64, XOR-swizzled LDS (2-way-free ds_read_b128)
// MODE 0: bias->bf16, 1: bias+gelu->bf16, 2: bias + resid -> f32 d_out w/ row guard
template<int MODE>
__global__ __launch_bounds__(256) void k_gemm(
    const u16* __restrict__ A, const u16* __restrict__ Bt,
    const float* __restrict__ bias, u16* __restrict__ Cb,
    float* __restrict__ outp, const u16* __restrict__ resid,
    int N, int K, int row_off) {
  __shared__ __align__(16) u16 As[128 * 64];   // 16 KB, row = 128 B (8 x 16B slots)
  __shared__ __align__(16) u16 Bs[128 * 64];
  int t = threadIdx.x;
  int m0 = blockIdx.y * 128, n0 = blockIdx.x * 128;
  int lane = t & 63, wave = t >> 6;
  int lo = lane & 15, hi = lane >> 4;
  int wr = (wave >> 1) * 64, wc = (wave & 1) * 64;
  // staging: per gload16, wave covers 8 rows x 128 B. physical slot p of row r
  // holds logical 16B-slot p ^ (r&7)  -> pre-swizzle the global source address.
  int rl = lane >> 3;                  // row within 8-row chunk (== row&7)
  int sl = (lane & 7) ^ rl;            // pre-swizzled logical slot
  const u16* Ag = A + (size_t)(m0 + wave * 32 + rl) * K + sl * 8;
  const u16* Bg = Bt + (size_t)(n0 + wave * 32 + rl) * K + sl * 8;
  u16* Al = As + (wave * 32) * 64;     // wave-uniform linear LDS dest
  u16* Bl = Bs + (wave * 32) * 64;
  f4v acc[4][4];
  #pragma unroll
  for (int m = 0; m < 4; m++)
    #pragma unroll
    for (int n = 0; n < 4; n++) acc[m][n] = (f4v)(0.0f);
  for (int kt = 0; kt < K; kt += 64) {
    __syncthreads();
    #pragma unroll
    for (int g = 0; g < 4; g++) {
      gload16(Ag + (size_t)(g * 8) * K + kt, Al + g * 8 * 64);
      gload16(Bg + (size_t)(g * 8) * K + kt, Bl + g * 8 * 64);
    }
    __syncthreads();
    #pragma unroll
    for (int kk = 0; kk < 2; kk++) {
      s8v af[4], bfr[4];
      #pragma unroll
      for (int m = 0; m < 4; m++) {
        int row = wr + m * 16 + lo;
        af[m] = *(const s8v*)(As + row * 64 + (((kk * 4 + hi) ^ (row & 7)) * 8));
      }
      #pragma unroll
      for (int n = 0; n < 4; n++) {
        int row = wc + n * 16 + lo;
        bfr[n] = *(const s8v*)(Bs + row * 64 + (((kk * 4 + hi) ^ (row & 7)) * 8));
      }
      #pragma unroll
      for (int m = 0; m < 4; m++)
        #pragma unroll
        for (int n = 0; n < 4; n++)
          acc[m][n] = __builtin_amdgcn_mfma_f32_16x16x32_bf16(af[m], bfr[n], acc[m][n], 0, 0, 0);
    }
  }
  #pragma unroll
  for (int m = 0; m < 4; m++) {
    int grow = m0 + wr + m * 16 + hi * 4;
    #pragma unroll
    for (int n = 0; n < 4; n++) {
      int gcol = n0 + wc + n * 16 + lo;
      float bv = bias[gcol];
      #pragma unroll
      for (int r = 0; r < 4; r++) {
        float val = acc[m][n][r] + bv;
        size_t idx = (size_t)(grow + r) * N + gcol;
        if (MODE == 0) {
          Cb[idx] = f2b(val);
        } else if (MODE == 1) {
          // gelu(x) ~= x * sigmoid(1.5957691x + 0.0713548x^3), |err|<3e-3
          float u = __builtin_fmaf(0.0713548163f * val, val * val, 1.5957691216f * val);
          float gl = val * __builtin_amdgcn_rcpf(1.0f + __expf(-u));
          Cb[idx] = f2b(gl);
        } else {
          int orow = grow + r + row_off;
          if (orow < M_FULL) {
            size_t oi = (size_t)orow * DIM + gcol;
            outp[oi] = val + b2f(resid[oi]);
          }
        }
      }
    }
  }
}

// ---------------- MFMA attention: one wave per window, 12 heads serial ----------------
__global__ __launch_bounds__(256) void k_attn2(const u16* __restrict__ qkv,
                                               const float* __restrict__ ADD,
                                               u16* __restrict__ ao, int win0) {
  __shared__ u16 PT[4][64][76];   // P transposed: PT[j][i] (+12 pad: 2-way-free banks)
  __shared__ u16 VT[4][32][76];   // V transposed: VT[d][j]
  int wid = threadIdx.x >> 6, lane = threadIdx.x & 63;
  int lo = lane & 15, hi = lane >> 4;
  int win_l = blockIdx.x * 4 + wid;
  int nw = (win0 + win_l) & 63;
  int wh = nw >> 3, ww = nw & 7;
  int cls = ((wh == 7) ? 2 : 0) + ((ww == 7) ? 1 : 0);
  size_t rowbase = (size_t)win_l * NTOK;
  u16 (*pt)[76] = PT[wid];
  u16 (*vt)[76] = VT[wid];

  int rcl[4];
  #pragma unroll
  for (int ti = 0; ti < 4; ti++) {
    int r = ti * 16 + lo;
    rcl[ti] = r < NTOK ? r : NTOK - 1;      // clamped fragment row
  }
  int jrow = lane < NTOK ? lane : NTOK - 1; // clamped V row for staging

  for (int h = 0; h < HEADS; h++) {
    // ---- fragments of Q,K straight from global; S = Q.K^T ----
    s8v af[4], bf[4];
    #pragma unroll
    for (int ti = 0; ti < 4; ti++) {
      af[ti] = *(const s8v*)(qkv + (rowbase + rcl[ti]) * 1152 + h * 32 + hi * 8);
      bf[ti] = *(const s8v*)(qkv + (rowbase + rcl[ti]) * 1152 + 384 + h * 32 + hi * 8);
    }
    f4v st[4][4];
    #pragma unroll
    for (int mi = 0; mi < 4; mi++)
      #pragma unroll
      for (int ni = 0; ni < 4; ni++)
        st[mi][ni] = __builtin_amdgcn_mfma_f32_16x16x32_bf16(af[mi], bf[ni], (f4v)(0.0f), 0, 0, 0);

    // ---- stage V^T into LDS (overlaps with MFMA latency) ----
    {
      const u16* vsrc = qkv + (rowbase + jrow) * 1152 + 768 + h * 32;
      #pragma unroll
      for (int d0 = 0; d0 < 32; d0 += 8) {
        s8v v = *(const s8v*)(vsrc + d0);
        #pragma unroll
        for (int e = 0; e < 8; e++) vt[d0 + e][lane] = (u16)v[e];
      }
    }

    // ---- bias + mask (precomputed), pad cols -> -inf ----
    const float* addb = ADD + ((size_t)cls * HEADS + h) * (NTOK * NTOK);
    #pragma unroll
    for (int mi = 0; mi < 4; mi++)
      #pragma unroll
      for (int ni = 0; ni < 4; ni++) {
        int jj = ni * 16 + lo;
        #pragma unroll
        for (int r = 0; r < 4; r++) {
          int i = mi * 16 + hi * 4 + r;
          if (jj < NTOK) {
            int ic = i < NTOK ? i : NTOK - 1;
            st[mi][ni][r] += addb[ic * NTOK + jj];
          } else st[mi][ni][r] = -1e30f;
        }
      }

    // ---- in-register row softmax (reduce over lo-16 group) ----
    float invl[4][4];
    #pragma unroll
    for (int mi = 0; mi < 4; mi++)
      #pragma unroll
      for (int r = 0; r < 4; r++) {
        float m = fmaxf(fmaxf(st[mi][0][r], st[mi][1][r]), fmaxf(st[mi][2][r], st[mi][3][r]));
        #pragma unroll
        for (int msk = 1; msk < 16; msk <<= 1) m = fmaxf(m, __shfl_xor(m, msk));
        float s = 0.f;
        #pragma unroll
        for (int ni = 0; ni < 4; ni++) {
          float p = __expf(st[mi][ni][r] - m);
          st[mi][ni][r] = p;
          s += p;
        }
        #pragma unroll
        for (int msk = 1; msk < 16; msk <<= 1) s += __shfl_xor(s, msk);
        invl[mi][r] = 1.0f / s;
      }

    // ---- P -> PT bf16 (b64 writes, 4 rows i per write) ----
    #pragma unroll
    for (int ni = 0; ni < 4; ni++)
      #pragma unroll
      for (int mi = 0; mi < 4; mi++) {
        ushort4 pk;
        pk.x = f2b(st[mi][ni][0]); pk.y = f2b(st[mi][ni][1]);
        pk.z = f2b(st[mi][ni][2]); pk.w = f2b(st[mi][ni][3]);
        *(ushort4*)(&pt[ni * 16 + lo][mi * 16 + hi * 4]) = pk;
      }

    // ---- O = P.V ----
    f4v ot[4][2];
    #pragma unroll
    for (int mi = 0; mi < 4; mi++)
      #pragma unroll
      for (int dt = 0; dt < 2; dt++) ot[mi][dt] = (f4v)(0.0f);
    #pragma unroll
    for (int kt = 0; kt < 2; kt++) {
      s8v pa[4], vb[2];
      #pragma unroll
      for (int mi = 0; mi < 4; mi++) {
        s8v p;
        #pragma unroll
        for (int e = 0; e < 8; e++) p[e] = (short)pt[kt * 32 + hi * 8 + e][mi * 16 + lo];
        pa[mi] = p;
      }
      #pragma unroll
      for (int dt = 0; dt < 2; dt++) {
        short4 a = *(const short4*)(&vt[dt * 16 + lo][kt * 32 + hi * 8]);
        short4 b = *(const short4*)(&vt[dt * 16 + lo][kt * 32 + hi * 8 + 4]);
        s8v v; v[0] = a.x; v[1] = a.y; v[2] = a.z; v[3] = a.w;
               v[4] = b.x; v[5] = b.y; v[6] = b.z; v[7] = b.w;
        vb[dt] = v;
      }
      #pragma unroll
      for (int mi = 0; mi < 4; mi++)
        #pragma unroll
        for (int dt = 0; dt < 2; dt++)
          ot[mi][dt] = __builtin_amdgcn_mfma_f32_16x16x32_bf16(pa[mi], vb[dt], ot[mi][dt], 0, 0, 0);
    }

    // ---- scale + store ----
    #pragma unroll
    for (int mi = 0; mi < 4; mi++)
      #pragma unroll
      for (int r = 0; r < 4; r++) {
        int i = mi * 16 + hi * 4 + r;
        if (i < NTOK) {
          u16* op = ao + (rowbase + i) * DIM + h * 32 + lo;
          op[0]  = f2b(ot[mi][0][r] * invl[mi][r]);
          op[16] = f2b(ot[mi][1][r] * invl[mi][r]);
        }
      }
  }
}

// ---------------- un-window + roll(+3,+3) + residual + LN2 -> x2 bf16 ----------------
__global__ void k_ln2(const float* __restrict__ x, const u16* __restrict__ proj,
                      const float* __restrict__ g, const float* __restrict__ b,
                      u16* __restrict__ x2b) {
  int wid = threadIdx.x >> 6, lane = threadIdx.x & 63;
  int r = blockIdx.x * 4 + wid;
  u16* dst = x2b + (size_t)r * DIM;
  if (r >= M_FULL) {
    u16 z = f2b(0.0f);
    #pragma unroll
    for (int e = 0; e < 6; e++) dst[lane + e * 64] = z;
    return;
  }
  int bi = r / TOKENS, tk = r % TOKENS;
  const float* xs = x + (size_t)r * DIM;
  float v[6];
  if (tk == 0) {
    #pragma unroll
    for (int e = 0; e < 6; e++) v[e] = xs[lane + e * 64];
  } else {
    int p = tk - 1, hh = p / 56, wp = p % 56;
    int a = (hh + 53) % 56, bw = (wp + 53) % 56;   // inverse roll by +3
    int wh = a / 7, ii = a % 7, w2 = bw / 7, jj = bw % 7;
    size_t prow = ((size_t)bi * 64 + wh * 8 + w2) * NTOK + ii * 7 + jj;
    const u16* ps = proj + prow * DIM;
    #pragma unroll
    for (int e = 0; e < 6; e++) v[e] = xs[lane + e * 64] + b2f(ps[lane + e * 64]);
  }
  float s = v[0] + v[1] + v[2] + v[3] + v[4] + v[5];
  #pragma unroll
  for (int m = 1; m < 64; m <<= 1) s += __shfl_xor(s, m);
  float mu = s * (1.0f / 384.0f);
  float q = 0.f;
  #pragma unroll
  for (int e = 0; e < 6; e++) { float d = v[e] - mu; q += d * d; }
  #pragma unroll
  for (int m = 1; m < 64; m <<= 1) q += __shfl_xor(q, m);
  float rstd = rsqrtf(q * (1.0f / 384.0f) + 1e-5f);
  #pragma unroll
  for (int e = 0; e < 6; e++) {
    int c = lane + e * 64;
    dst[c] = f2b((v[e] - mu) * rstd * g[c] + b[c]);
  }
}

extern "C" void kernel_launch(void* const* d_in, const int* in_sizes, int n_in,
                              void* d_out, int out_size, void* d_ws, size_t ws_size,
                              hipStream_t stream) {
  const float* x      = (const float*)d_in[0];
  const float* n1g    = (const float*)d_in[1];
  const float* n1b    = (const float*)d_in[2];
  const float* qkv_w  = (const float*)d_in[3];
  const float* qkv_b  = (const float*)d_in[4];
  const float* rpb    = (const float*)d_in[5];
  const float* proj_w = (const float*)d_in[6];
  const float* proj_b = (const float*)d_in[7];
  const float* n2g    = (const float*)d_in[8];
  const float* n2b    = (const float*)d_in[9];
  const float* fc1_w  = (const float*)d_in[10];
  const float* fc1_b  = (const float*)d_in[11];
  const float* fc2_w  = (const float*)d_in[12];
  const float* fc2_b  = (const float*)d_in[13];
  float* outp = (float*)d_out;

  auto al = [](size_t v) { return (v + 255) & ~(size_t)255; };
  const int cand[8][2] = {{1,1},{1,2},{2,2},{2,4},{4,4},{4,8},{8,8},{16,16}};
  int NC1 = 16, NC2 = 16;
  for (int ci = 0; ci < 8; ci++) {
    int c1 = cand[ci][0], c2 = cand[ci][1];
    int cbb = (785 + c2 - 1) / c2;
    size_t tot = al(884736) + al(294912) + al(1179648) + al(1179648) + al(4608)
               + al(460992)
               + al((size_t)(M_ATTN / c1) * 768)
               + al((size_t)(M_ATTN / c1) * 2304)
               + al((size_t)M_ATTN * 768)
               + al((size_t)M_PAD * 768)
               + al((size_t)cbb * 128 * 1536 * 2);
    if (tot <= ws_size) { NC1 = c1; NC2 = c2; break; }
  }
  char* p = (char*)d_ws;
  auto take = [&](size_t bytes) { char* r = p; p += al(bytes); return r; };
  u16* wt_qkv  = (u16*)take(884736);
  u16* wt_proj = (u16*)take(294912);
  u16* wt_fc1  = (u16*)take(1179648);
  u16* wt_fc2  = (u16*)take(1179648);
  float* qkvb_s = (float*)take(4608);
  float* ADDt   = (float*)take(460992);
  int chunkM = M_ATTN / NC1;
  u16* XW   = (u16*)take((size_t)chunkM * 768);
  u16* QKV  = (u16*)take((size_t)chunkM * 2304);
  u16* PROJ = (u16*)take((size_t)M_ATTN * 768);
  u16* X2B  = (u16*)take((size_t)M_PAD * 768);
  int cb = (785 + NC2 - 1) / NC2;
  u16* FC1  = (u16*)take((size_t)cb * 128 * 1536 * 2);
  u16* AO = XW;   // alias: XW dead after QKV GEMM

  k_convert<<<2304, 256, 0, stream>>>(qkv_w, qkv_b, proj_w, fc1_w, fc2_w,
                                      wt_qkv, qkvb_s, wt_proj, wt_fc1, wt_fc2);
  k_addtab<<<451, 256, 0, stream>>>(rpb, ADDt);
  int chunkWin = chunkM / NTOK;
  for (int c = 0; c < NC1; c++) {
    int t0 = c * chunkM;
    k_ln1<<<chunkM / 4, 256, 0, stream>>>(x, n1g, n1b, XW, t0);
    k_gemm<0><<<dim3(9, chunkM / 128), 256, 0, stream>>>(XW, wt_qkv, qkvb_s, QKV,
                                                         nullptr, nullptr, 1152, 384, 0);
    k_attn2<<<chunkWin / 4, 256, 0, stream>>>(QKV, ADDt, AO, c * chunkWin);
    k_gemm<0><<<dim3(3, chunkM / 128), 256, 0, stream>>>(AO, wt_proj, proj_b,
                                                         PROJ + (size_t)t0 * DIM,
                                                         nullptr, nullptr, 384, 384, 0);
  }
  k_ln2<<<M_PAD / 4, 256, 0, stream>>>(x, PROJ, n2g, n2b, X2B);
  for (int c = 0; c < NC2; c++) {
    int rb0 = c * cb;
    int nb = 785 - rb0; if (nb > cb) nb = cb; if (nb <= 0) break;
    k_gemm<1><<<dim3(12, nb), 256, 0, stream>>>(X2B + (size_t)rb0 * 128 * DIM, wt_fc1,
                                                fc1_b, FC1, nullptr, nullptr, 1536, 384, 0);
    k_gemm<2><<<dim3(3, nb), 256, 0, stream>>>(FC1, wt_fc2, fc2_b, nullptr, outp, X2B,
                                               384, 1536, rb0 * 128);
  }
}

// Round 4
// 1007.474 us; speedup vs baseline: 1.4388x; 1.0054x over previous
//
#include <hip/hip_runtime.h>
#include <hip/hip_bf16.h>

#define DIM 384
#define HEADS 12
#define NTOK 49
#define TOKENS 3137
#define M_ATTN 100352   // 32*64*49 window rows
#define M_FULL 100384   // 32*3137 token rows
#define M_PAD  100480   // 785*128
#define SCALEQ 0.17677669529663687f

typedef __attribute__((ext_vector_type(8))) short s8v;
typedef __attribute__((ext_vector_type(4))) float f4v;
typedef unsigned short u16;

__device__ __forceinline__ float b2f(int s) {
  union { unsigned u; float f; } c; c.u = ((unsigned)(s & 0xffff)) << 16; return c.f;
}
__device__ __forceinline__ u16 f2b(float f) {
  __hip_bfloat16 h = __float2bfloat16(f);
  return *reinterpret_cast<u16*>(&h);
}
__device__ __forceinline__ void gload16(const void* g, void* l) {
  __builtin_amdgcn_global_load_lds((const __attribute__((address_space(1))) void*)g,
                                   (__attribute__((address_space(3))) void*)l, 16, 0, 0);
}

// ---------------- weight convert: f32 -> bf16, transposed to [N][K] ----------------
__global__ void k_convert(const float* __restrict__ qkv_w, const float* __restrict__ qkv_b,
                          const float* __restrict__ proj_w, const float* __restrict__ fc1_w,
                          const float* __restrict__ fc2_w,
                          u16* __restrict__ wt_qkv, float* __restrict__ qkvb_s,
                          u16* __restrict__ wt_proj, u16* __restrict__ wt_fc1,
                          u16* __restrict__ wt_fc2) {
  int i = blockIdx.x * 256 + threadIdx.x;
  if (i < 1152 * 384) { int n = i / 384, k = i % 384;
    float v = qkv_w[(size_t)k * 1152 + n]; if (n < 384) v *= SCALEQ; wt_qkv[i] = f2b(v); }
  if (i < 1152) qkvb_s[i] = qkv_b[i] * (i < 384 ? SCALEQ : 1.0f);
  if (i < 384 * 384) { int n = i / 384, k = i % 384; wt_proj[i] = f2b(proj_w[(size_t)k * 384 + n]); }
  if (i < 1536 * 384) { int n = i / 384, k = i % 384; wt_fc1[i] = f2b(fc1_w[(size_t)k * 1536 + n]); }
  if (i < 384 * 1536) { int n = i / 1536, k = i % 1536; wt_fc2[i] = f2b(fc2_w[(size_t)k * 384 + n]); }
}

// ---------------- ADD table: bias + shift mask per window class ----------------
__global__ void k_addtab(const float* __restrict__ rpb, float* __restrict__ ADD) {
  int idx = blockIdx.x * 256 + threadIdx.x;
  if (idx >= 4 * HEADS * NTOK * NTOK) return;
  int j = idx % NTOK, t = idx / NTOK;
  int i = t % NTOK; t /= NTOK;
  int h = t % HEADS; int cls = t / HEADS;
  int ii = i / 7, jj = i % 7, ji = j / 7, j2 = j % 7;
  int rpi = (ii - ji + 6) * 13 + (jj - j2 + 6);
  float v = rpb[rpi * HEADS + h];
  int rh = (cls & 2) ? (ii < 4 ? 1 : 2) : 0;
  int rw = (cls & 1) ? (jj < 4 ? 1 : 2) : 0;
  int sh = (cls & 2) ? (ji < 4 ? 1 : 2) : 0;
  int sw = (cls & 1) ? (j2 < 4 ? 1 : 2) : 0;
  if (rh != sh || rw != sw) v -= 100.0f;
  ADD[idx] = v;
}

// ---------------- LN1 + roll(-3,-3) + window partition -> xw bf16 ----------------
__global__ void k_ln1(const float* __restrict__ x, const float* __restrict__ g,
                      const float* __restrict__ b, u16* __restrict__ xw, int t0) {
  int wid = threadIdx.x >> 6, lane = threadIdx.x & 63;
  int t = t0 + blockIdx.x * 4 + wid;          // global window-row index
  int bi = t / 3136, rem = t % 3136;
  int win = rem / NTOK, n = rem % NTOK;
  int wh = win >> 3, ww = win & 7, ii = n / 7, jj = n % 7;
  int h = (wh * 7 + ii + 3) % 56;
  int w = (ww * 7 + jj + 3) % 56;
  const float* src = x + ((size_t)bi * TOKENS + 1 + h * 56 + w) * DIM;
  float v[6];
  #pragma unroll
  for (int e = 0; e < 6; e++) v[e] = src[lane + e * 64];
  float s = v[0] + v[1] + v[2] + v[3] + v[4] + v[5];
  #pragma unroll
  for (int m = 1; m < 64; m <<= 1) s += __shfl_xor(s, m);
  float mu = s * (1.0f / 384.0f);
  float q = 0.f;
  #pragma unroll
  for (int e = 0; e < 6; e++) { float d = v[e] - mu; q += d * d; }
  #pragma unroll
  for (int m = 1; m < 64; m <<= 1) q += __shfl_xor(q, m);
  float rstd = rsqrtf(q * (1.0f / 384.0f) + 1e-5f);
  u16* dst = xw + (size_t)(t - t0) * DIM;
  #pragma unroll
  for (int e = 0; e < 6; e++) {
    int c = lane + e * 64;
    dst[c] = f2b((v[e] - mu) * rstd * g[c] + b[c]);
  }
}

// ---------------- bf16 MFMA GEMM: double-buffered, counted-vmcnt pipeline (T3+T4),
// ---------------- XOR-swizzled LDS (T2, verified 0-conflict), XCD tile remap (T1).
// MODE 0: bias->bf16, 1: bias+gelu->bf16, 2: bias + resid -> f32 d_out w/ row guard
template<int MODE>
__global__ __launch_bounds__(256) void k_gemm(
    const u16* __restrict__ A, const u16* __restrict__ Bt,
    const float* __restrict__ bias, u16* __restrict__ Cb,
    float* __restrict__ outp, const u16* __restrict__ resid,
    int N, int K, int row_off) {
  __shared__ __align__(16) u16 As[2][128 * 64];   // 2 x 16 KB, row = 128 B
  __shared__ __align__(16) u16 Bs[2][128 * 64];
  // T1: bijective XCD-contiguous tile remap (m204). HW assigns dispatch id -> XCD
  // round-robin; make each XCD own a contiguous tile range so A-panels stay in one L2.
  int gx = gridDim.x;
  int lid = blockIdx.y * gx + blockIdx.x;
  int nwg = gx * gridDim.y;
  int q = nwg >> 3, r = nwg & 7;
  int xcd = lid & 7, loc = lid >> 3;
  int tile = (xcd < r ? xcd * (q + 1) : r * (q + 1) + (xcd - r) * q) + loc;
  int m0 = (tile / gx) * 128, n0 = (tile % gx) * 128;
  int t = threadIdx.x;
  int lane = t & 63, wave = t >> 6;
  int lo = lane & 15, hi = lane >> 4;
  int wr = (wave >> 1) * 64, wc = (wave & 1) * 64;
  // staging: per gload16, wave covers 8 rows x 128 B. physical slot p of row r
  // holds logical 16B-slot p ^ (r&7)  -> pre-swizzle the global source address.
  int rl = lane >> 3;                  // row within 8-row chunk (== row&7)
  int sl = (lane & 7) ^ rl;            // pre-swizzled logical slot
  const u16* Ag = A + (size_t)(m0 + wave * 32 + rl) * K + sl * 8;
  const u16* Bg = Bt + (size_t)(n0 + wave * 32 + rl) * K + sl * 8;
  f4v acc[4][4];
  #pragma unroll
  for (int m = 0; m < 4; m++)
    #pragma unroll
    for (int n = 0; n < 4; n++) acc[m][n] = (f4v)(0.0f);
  int nt = K >> 6;
#define STAGE(buf, kt) do {                                              \
    u16* al_ = As[buf] + wave * 32 * 64;                                 \
    u16* bl_ = Bs[buf] + wave * 32 * 64;                                 \
    _Pragma("unroll")                                                    \
    for (int g_ = 0; g_ < 4; g_++) {                                     \
      gload16(Ag + (size_t)(g_ * 8) * K + (kt), al_ + g_ * 8 * 64);      \
      gload16(Bg + (size_t)(g_ * 8) * K + (kt), bl_ + g_ * 8 * 64);      \
    } } while (0)
  STAGE(0, 0);                          // prologue: tile 0 in flight (8 loads)
  for (int kt = 0; kt < nt; ++kt) {
    int c = kt & 1;
    if (kt + 1 < nt) {
      STAGE(1 - c, (kt + 1) << 6);      // issue next tile: 8 more loads in flight
      asm volatile("s_waitcnt vmcnt(8)" ::: "memory");   // oldest 8 (tile kt) landed
    } else {
      asm volatile("s_waitcnt vmcnt(0)" ::: "memory");
    }
    __builtin_amdgcn_s_barrier();       // B1: tile kt visible to all waves
    __builtin_amdgcn_sched_barrier(0);
    s8v af[2][4], bfr[2][4];
    #pragma unroll
    for (int kk = 0; kk < 2; kk++) {
      #pragma unroll
      for (int m = 0; m < 4; m++) {
        int row = wr + m * 16 + lo;
        af[kk][m] = *(const s8v*)(As[c] + row * 64 + (((kk * 4 + hi) ^ (row & 7)) * 8));
      }
      #pragma unroll
      for (int n = 0; n < 4; n++) {
        int row = wc + n * 16 + lo;
        bfr[kk][n] = *(const s8v*)(Bs[c] + row * 64 + (((kk * 4 + hi) ^ (row & 7)) * 8));
      }
    }
    asm volatile("s_waitcnt lgkmcnt(0)" ::: "memory");   // frags in regs
    __builtin_amdgcn_sched_barrier(0);                   // rule #18 fence
    __builtin_amdgcn_s_barrier();       // B2: all waves done reading buf[c]
    __builtin_amdgcn_sched_barrier(0);
    __builtin_amdgcn_s_setprio(1);
    #pragma unroll
    for (int kk = 0; kk < 2; kk++)
      #pragma unroll
      for (int m = 0; m < 4; m++)
        #pragma unroll
        for (int n = 0; n < 4; n++)
          acc[m][n] = __builtin_amdgcn_mfma_f32_16x16x32_bf16(af[kk][m], bfr[kk][n], acc[m][n], 0, 0, 0);
    __builtin_amdgcn_s_setprio(0);
  }
#undef STAGE
  #pragma unroll
  for (int m = 0; m < 4; m++) {
    int grow = m0 + wr + m * 16 + hi * 4;
    #pragma unroll
    for (int n = 0; n < 4; n++) {
      int gcol = n0 + wc + n * 16 + lo;
      float bv = bias[gcol];
      #pragma unroll
      for (int r2 = 0; r2 < 4; r2++) {
        float val = acc[m][n][r2] + bv;
        size_t idx = (size_t)(grow + r2) * N + gcol;
        if (MODE == 0) {
          Cb[idx] = f2b(val);
        } else if (MODE == 1) {
          // gelu(x) ~= x * sigmoid(1.5957691x + 0.0713548x^3), |err|<3e-3
          float u = __builtin_fmaf(0.0713548163f * val, val * val, 1.5957691216f * val);
          float gl = val * __builtin_amdgcn_rcpf(1.0f + __expf(-u));
          Cb[idx] = f2b(gl);
        } else {
          int orow = grow + r2 + row_off;
          if (orow < M_FULL) {
            size_t oi = (size_t)orow * DIM + gcol;
            outp[oi] = val + b2f(resid[oi]);
          }
        }
      }
    }
  }
}

// ---------------- MFMA attention: one wave per window, 12 heads serial ----------------
__global__ __launch_bounds__(256) void k_attn2(const u16* __restrict__ qkv,
                                               const float* __restrict__ ADD,
                                               u16* __restrict__ ao, int win0) {
  __shared__ u16 PT[4][64][76];   // P transposed: PT[j][i] (+12 pad: 2-way-free banks)
  __shared__ u16 VT[4][32][76];   // V transposed: VT[d][j]
  int wid = threadIdx.x >> 6, lane = threadIdx.x & 63;
  int lo = lane & 15, hi = lane >> 4;
  int win_l = blockIdx.x * 4 + wid;
  int nw = (win0 + win_l) & 63;
  int wh = nw >> 3, ww = nw & 7;
  int cls = ((wh == 7) ? 2 : 0) + ((ww == 7) ? 1 : 0);
  size_t rowbase = (size_t)win_l * NTOK;
  u16 (*pt)[76] = PT[wid];
  u16 (*vt)[76] = VT[wid];

  int rcl[4];
  #pragma unroll
  for (int ti = 0; ti < 4; ti++) {
    int r = ti * 16 + lo;
    rcl[ti] = r < NTOK ? r : NTOK - 1;      // clamped fragment row
  }
  int jrow = lane < NTOK ? lane : NTOK - 1; // clamped V row for staging

  for (int h = 0; h < HEADS; h++) {
    // ---- fragments of Q,K straight from global; S = Q.K^T ----
    s8v af[4], bf[4];
    #pragma unroll
    for (int ti = 0; ti < 4; ti++) {
      af[ti] = *(const s8v*)(qkv + (rowbase + rcl[ti]) * 1152 + h * 32 + hi * 8);
      bf[ti] = *(const s8v*)(qkv + (rowbase + rcl[ti]) * 1152 + 384 + h * 32 + hi * 8);
    }
    f4v st[4][4];
    #pragma unroll
    for (int mi = 0; mi < 4; mi++)
      #pragma unroll
      for (int ni = 0; ni < 4; ni++)
        st[mi][ni] = __builtin_amdgcn_mfma_f32_16x16x32_bf16(af[mi], bf[ni], (f4v)(0.0f), 0, 0, 0);

    // ---- stage V^T into LDS (overlaps with MFMA latency) ----
    {
      const u16* vsrc = qkv + (rowbase + jrow) * 1152 + 768 + h * 32;
      #pragma unroll
      for (int d0 = 0; d0 < 32; d0 += 8) {
        s8v v = *(const s8v*)(vsrc + d0);
        #pragma unroll
        for (int e = 0; e < 8; e++) vt[d0 + e][lane] = (u16)v[e];
      }
    }

    // ---- bias + mask (precomputed), pad cols -> -inf ----
    const float* addb = ADD + ((size_t)cls * HEADS + h) * (NTOK * NTOK);
    #pragma unroll
    for (int mi = 0; mi < 4; mi++)
      #pragma unroll
      for (int ni = 0; ni < 4; ni++) {
        int jj = ni * 16 + lo;
        #pragma unroll
        for (int r = 0; r < 4; r++) {
          int i = mi * 16 + hi * 4 + r;
          if (jj < NTOK) {
            int ic = i < NTOK ? i : NTOK - 1;
            st[mi][ni][r] += addb[ic * NTOK + jj];
          } else st[mi][ni][r] = -1e30f;
        }
      }

    // ---- in-register row softmax (reduce over lo-16 group) ----
    float invl[4][4];
    #pragma unroll
    for (int mi = 0; mi < 4; mi++)
      #pragma unroll
      for (int r = 0; r < 4; r++) {
        float m = fmaxf(fmaxf(st[mi][0][r], st[mi][1][r]), fmaxf(st[mi][2][r], st[mi][3][r]));
        #pragma unroll
        for (int msk = 1; msk < 16; msk <<= 1) m = fmaxf(m, __shfl_xor(m, msk));
        float s = 0.f;
        #pragma unroll
        for (int ni = 0; ni < 4; ni++) {
          float p = __expf(st[mi][ni][r] - m);
          st[mi][ni][r] = p;
          s += p;
        }
        #pragma unroll
        for (int msk = 1; msk < 16; msk <<= 1) s += __shfl_xor(s, msk);
        invl[mi][r] = 1.0f / s;
      }

    // ---- P -> PT bf16 (b64 writes, 4 rows i per write) ----
    #pragma unroll
    for (int ni = 0; ni < 4; ni++)
      #pragma unroll
      for (int mi = 0; mi < 4; mi++) {
        ushort4 pk;
        pk.x = f2b(st[mi][ni][0]); pk.y = f2b(st[mi][ni][1]);
        pk.z = f2b(st[mi][ni][2]); pk.w = f2b(st[mi][ni][3]);
        *(ushort4*)(&pt[ni * 16 + lo][mi * 16 + hi * 4]) = pk;
      }

    // ---- O = P.V ----
    f4v ot[4][2];
    #pragma unroll
    for (int mi = 0; mi < 4; mi++)
      #pragma unroll
      for (int dt = 0; dt < 2; dt++) ot[mi][dt] = (f4v)(0.0f);
    #pragma unroll
    for (int kt = 0; kt < 2; kt++) {
      s8v pa[4], vb[2];
      #pragma unroll
      for (int mi = 0; mi < 4; mi++) {
        s8v p;
        #pragma unroll
        for (int e = 0; e < 8; e++) p[e] = (short)pt[kt * 32 + hi * 8 + e][mi * 16 + lo];
        pa[mi] = p;
      }
      #pragma unroll
      for (int dt = 0; dt < 2; dt++) {
        short4 a = *(const short4*)(&vt[dt * 16 + lo][kt * 32 + hi * 8]);
        short4 b = *(const short4*)(&vt[dt * 16 + lo][kt * 32 + hi * 8 + 4]);
        s8v v; v[0] = a.x; v[1] = a.y; v[2] = a.z; v[3] = a.w;
               v[4] = b.x; v[5] = b.y; v[6] = b.z; v[7] = b.w;
        vb[dt] = v;
      }
      #pragma unroll
      for (int mi = 0; mi < 4; mi++)
        #pragma unroll
        for (int dt = 0; dt < 2; dt++)
          ot[mi][dt] = __builtin_amdgcn_mfma_f32_16x16x32_bf16(pa[mi], vb[dt], ot[mi][dt], 0, 0, 0);
    }

    // ---- scale + store ----
    #pragma unroll
    for (int mi = 0; mi < 4; mi++)
      #pragma unroll
      for (int r = 0; r < 4; r++) {
        int i = mi * 16 + hi * 4 + r;
        if (i < NTOK) {
          u16* op = ao + (rowbase + i) * DIM + h * 32 + lo;
          op[0]  = f2b(ot[mi][0][r] * invl[mi][r]);
          op[16] = f2b(ot[mi][1][r] * invl[mi][r]);
        }
      }
  }
}

// ---------------- un-window + roll(+3,+3) + residual + LN2 -> x2 bf16 ----------------
__global__ void k_ln2(const float* __restrict__ x, const u16* __restrict__ proj,
                      const float* __restrict__ g, const float* __restrict__ b,
                      u16* __restrict__ x2b) {
  int wid = threadIdx.x >> 6, lane = threadIdx.x & 63;
  int r = blockIdx.x * 4 + wid;
  u16* dst = x2b + (size_t)r * DIM;
  if (r >= M_FULL) {
    u16 z = f2b(0.0f);
    #pragma unroll
    for (int e = 0; e < 6; e++) dst[lane + e * 64] = z;
    return;
  }
  int bi = r / TOKENS, tk = r % TOKENS;
  const float* xs = x + (size_t)r * DIM;
  float v[6];
  if (tk == 0) {
    #pragma unroll
    for (int e = 0; e < 6; e++) v[e] = xs[lane + e * 64];
  } else {
    int p = tk - 1, hh = p / 56, wp = p % 56;
    int a = (hh + 53) % 56, bw = (wp + 53) % 56;   // inverse roll by +3
    int wh = a / 7, ii = a % 7, w2 = bw / 7, jj = bw % 7;
    size_t prow = ((size_t)bi * 64 + wh * 8 + w2) * NTOK + ii * 7 + jj;
    const u16* ps = proj + prow * DIM;
    #pragma unroll
    for (int e = 0; e < 6; e++) v[e] = xs[lane + e * 64] + b2f(ps[lane + e * 64]);
  }
  float s = v[0] + v[1] + v[2] + v[3] + v[4] + v[5];
  #pragma unroll
  for (int m = 1; m < 64; m <<= 1) s += __shfl_xor(s, m);
  float mu = s * (1.0f / 384.0f);
  float q = 0.f;
  #pragma unroll
  for (int e = 0; e < 6; e++) { float d = v[e] - mu; q += d * d; }
  #pragma unroll
  for (int m = 1; m < 64; m <<= 1) q += __shfl_xor(q, m);
  float rstd = rsqrtf(q * (1.0f / 384.0f) + 1e-5f);
  #pragma unroll
  for (int e = 0; e < 6; e++) {
    int c = lane + e * 64;
    dst[c] = f2b((v[e] - mu) * rstd * g[c] + b[c]);
  }
}

extern "C" void kernel_launch(void* const* d_in, const int* in_sizes, int n_in,
                              void* d_out, int out_size, void* d_ws, size_t ws_size,
                              hipStream_t stream) {
  const float* x      = (const float*)d_in[0];
  const float* n1g    = (const float*)d_in[1];
  const float* n1b    = (const float*)d_in[2];
  const float* qkv_w  = (const float*)d_in[3];
  const float* qkv_b  = (const float*)d_in[4];
  const float* rpb    = (const float*)d_in[5];
  const float* proj_w = (const float*)d_in[6];
  const float* proj_b = (const float*)d_in[7];
  const float* n2g    = (const float*)d_in[8];
  const float* n2b    = (const float*)d_in[9];
  const float* fc1_w  = (const float*)d_in[10];
  const float* fc1_b  = (const float*)d_in[11];
  const float* fc2_w  = (const float*)d_in[12];
  const float* fc2_b  = (const float*)d_in[13];
  float* outp = (float*)d_out;

  auto al = [](size_t v) { return (v + 255) & ~(size_t)255; };
  const int cand[8][2] = {{1,1},{1,2},{2,2},{2,4},{4,4},{4,8},{8,8},{16,16}};
  int NC1 = 16, NC2 = 16;
  for (int ci = 0; ci < 8; ci++) {
    int c1 = cand[ci][0], c2 = cand[ci][1];
    int cbb = (785 + c2 - 1) / c2;
    size_t tot = al(884736) + al(294912) + al(1179648) + al(1179648) + al(4608)
               + al(460992)
               + al((size_t)(M_ATTN / c1) * 768)
               + al((size_t)(M_ATTN / c1) * 2304)
               + al((size_t)M_ATTN * 768)
               + al((size_t)M_PAD * 768)
               + al((size_t)cbb * 128 * 1536 * 2);
    if (tot <= ws_size) { NC1 = c1; NC2 = c2; break; }
  }
  char* p = (char*)d_ws;
  auto take = [&](size_t bytes) { char* r = p; p += al(bytes); return r; };
  u16* wt_qkv  = (u16*)take(884736);
  u16* wt_proj = (u16*)take(294912);
  u16* wt_fc1  = (u16*)take(1179648);
  u16* wt_fc2  = (u16*)take(1179648);
  float* qkvb_s = (float*)take(4608);
  float* ADDt   = (float*)take(460992);
  int chunkM = M_ATTN / NC1;
  u16* XW   = (u16*)take((size_t)chunkM * 768);
  u16* QKV  = (u16*)take((size_t)chunkM * 2304);
  u16* PROJ = (u16*)take((size_t)M_ATTN * 768);
  u16* X2B  = (u16*)take((size_t)M_PAD * 768);
  int cb = (785 + NC2 - 1) / NC2;
  u16* FC1  = (u16*)take((size_t)cb * 128 * 1536 * 2);
  u16* AO = XW;   // alias: XW dead after QKV GEMM

  k_convert<<<2304, 256, 0, stream>>>(qkv_w, qkv_b, proj_w, fc1_w, fc2_w,
                                      wt_qkv, qkvb_s, wt_proj, wt_fc1, wt_fc2);
  k_addtab<<<451, 256, 0, stream>>>(rpb, ADDt);
  int chunkWin = chunkM / NTOK;
  for (int c = 0; c < NC1; c++) {
    int t0 = c * chunkM;
    k_ln1<<<chunkM / 4, 256, 0, stream>>>(x, n1g, n1b, XW, t0);
    k_gemm<0><<<dim3(9, chunkM / 128), 256, 0, stream>>>(XW, wt_qkv, qkvb_s, QKV,
                                                         nullptr, nullptr, 1152, 384, 0);
    k_attn2<<<chunkWin / 4, 256, 0, stream>>>(QKV, ADDt, AO, c * chunkWin);
    k_gemm<0><<<dim3(3, chunkM / 128), 256, 0, stream>>>(AO, wt_proj, proj_b,
                                                         PROJ + (size_t)t0 * DIM,
                                                         nullptr, nullptr, 384, 384, 0);
  }
  k_ln2<<<M_PAD / 4, 256, 0, stream>>>(x, PROJ, n2g, n2b, X2B);
  for (int c = 0; c < NC2; c++) {
    int rb0 = c * cb;
    int nb = 785 - rb0; if (nb > cb) nb = cb; if (nb <= 0) break;
    k_gemm<1><<<dim3(12, nb), 256, 0, stream>>>(X2B + (size_t)rb0 * 128 * DIM, wt_fc1,
                                                fc1_b, FC1, nullptr, nullptr, 1536, 384, 0);
    k_gemm<2><<<dim3(3, nb), 256, 0, stream>>>(FC1, wt_fc2, fc2_b, nullptr, outp, X2B,
                                               384, 1536, rb0 * 128);
  }
}